// Round 1
// baseline (325.772 us; speedup 1.0000x reference)
//
#include <hip/hip_runtime.h>

// FFNN Transducer fused forward, fp32 baseline.
// Inputs (setup_inputs order):
//  0 encoder_states (8,512,512) f32     1 encoder_states_size (8) i32
//  2 targets (8,64) i32                 3 targets_size (8) i32
//  4 emb (128,128) f32                  5 W1 (256,256)  6 b1 (256)
//  7 W2 (256,256)  8 b2 (256)           9 Wj1 (768,512) 10 bj1 (512)
// 11 Wj2 (512,128) 12 bj2 (128)
// Output: (8,512,65,128) f32, masked (zeros where t>=esz or u>tsz).
// Workspace: enc_proj 4096*512 f32 (8 MB) + pred_proj 520*512 f32 (1 MB).

#define VOCAB 128
#define EMBD  128
#define ENCD  512
#define PREDD 256
#define JOIND 512
#define NB    8
#define NT    512
#define NUT   64
#define UP1   65

__device__ __forceinline__ float frelu(float x) { return x > 0.f ? x : 0.f; }

// ---------------------------------------------------------------------------
// Kernel A: prediction network + projection through Wp (=Wj1[512:768]) + bj1.
// One block per (b,u) row; 256 threads.
// pproj[row][j] = pred(b,u) @ Wp[:,j] + bj1[j]
// ---------------------------------------------------------------------------
__global__ __launch_bounds__(256) void pred_net_kernel(
    const int* __restrict__ targets, const int* __restrict__ tsz,
    const float* __restrict__ emb,
    const float* __restrict__ W1, const float* __restrict__ b1,
    const float* __restrict__ W2, const float* __restrict__ b2,
    const float* __restrict__ Wj1, const float* __restrict__ bj1,
    float* __restrict__ pproj)
{
    const int row = blockIdx.x;          // 0..519
    const int b = row / UP1, u = row % UP1;
    if (u > tsz[b]) return;              // masked rows never read validly
    const int tid = threadIdx.x;
    __shared__ float e_s[256], p_s[256], q_s[256];

    // context tokens: c0 = most recent (targets[u-1]), c1 = targets[u-2]; pad=V-1
    const int c0 = (u >= 1) ? targets[b * NUT + u - 1] : (VOCAB - 1);
    const int c1 = (u >= 2) ? targets[b * NUT + u - 2] : (VOCAB - 1);
    e_s[tid] = (tid < EMBD) ? emb[c0 * EMBD + tid] : emb[c1 * EMBD + (tid - EMBD)];
    __syncthreads();

    // p = relu(e @ W1 + b1); thread tid owns output column tid
    {
        float a0 = 0.f, a1 = 0.f, a2 = 0.f, a3 = 0.f;
        #pragma unroll 8
        for (int k = 0; k < 256; k += 4) {
            a0 = fmaf(e_s[k + 0], W1[(k + 0) * PREDD + tid], a0);
            a1 = fmaf(e_s[k + 1], W1[(k + 1) * PREDD + tid], a1);
            a2 = fmaf(e_s[k + 2], W1[(k + 2) * PREDD + tid], a2);
            a3 = fmaf(e_s[k + 3], W1[(k + 3) * PREDD + tid], a3);
        }
        p_s[tid] = frelu((a0 + a1) + (a2 + a3) + b1[tid]);
    }
    __syncthreads();

    // pred = relu(p @ W2 + b2)
    {
        float a0 = 0.f, a1 = 0.f, a2 = 0.f, a3 = 0.f;
        #pragma unroll 8
        for (int k = 0; k < 256; k += 4) {
            a0 = fmaf(p_s[k + 0], W2[(k + 0) * PREDD + tid], a0);
            a1 = fmaf(p_s[k + 1], W2[(k + 1) * PREDD + tid], a1);
            a2 = fmaf(p_s[k + 2], W2[(k + 2) * PREDD + tid], a2);
            a3 = fmaf(p_s[k + 3], W2[(k + 3) * PREDD + tid], a3);
        }
        q_s[tid] = frelu((a0 + a1) + (a2 + a3) + b2[tid]);
    }
    __syncthreads();

    // pproj = pred @ Wp + bj1 (512 outputs; each thread does 2)
    #pragma unroll
    for (int h = 0; h < 2; ++h) {
        const int j = tid + h * 256;
        float a0 = 0.f, a1 = 0.f, a2 = 0.f, a3 = 0.f;
        #pragma unroll 8
        for (int k = 0; k < 256; k += 4) {
            a0 = fmaf(q_s[k + 0], Wj1[(size_t)(ENCD + k + 0) * JOIND + j], a0);
            a1 = fmaf(q_s[k + 1], Wj1[(size_t)(ENCD + k + 1) * JOIND + j], a1);
            a2 = fmaf(q_s[k + 2], Wj1[(size_t)(ENCD + k + 2) * JOIND + j], a2);
            a3 = fmaf(q_s[k + 3], Wj1[(size_t)(ENCD + k + 3) * JOIND + j], a3);
        }
        pproj[(size_t)row * JOIND + j] = (a0 + a1) + (a2 + a3) + bj1[j];
    }
}

// ---------------------------------------------------------------------------
// Kernel B: enc_proj = encoder_states @ We (=Wj1[0:512]).
// 64x64 tile per block, 256 threads, 4x4 per thread, K-chunks of 32.
// Skips row-tiles entirely above enc_size (outputs stay poison; joint masks).
// ---------------------------------------------------------------------------
__global__ __launch_bounds__(256) void enc_proj_kernel(
    const float* __restrict__ A, const float* __restrict__ Wj1,
    const int* __restrict__ esz, float* __restrict__ eproj)
{
    const int rTile = blockIdx.y, cTile = blockIdx.x;
    const int b = rTile >> 3;
    const int t0 = (rTile & 7) * 64;
    if (t0 >= esz[b]) return;
    const int row0 = rTile * 64, col0 = cTile * 64;
    const int tid = threadIdx.x;
    const int tx = tid & 15, ty = tid >> 4;

    __shared__ float At[32][68];   // [k][r], stride 68 breaks bank aliasing
    __shared__ float Bt[32][64];   // [k][c]

    float acc[4][4] = {};
    for (int kc = 0; kc < 512; kc += 32) {
        {   // stage A transposed: 64 rows x 32 k
            const int r  = tid >> 3;
            const int kq = (tid & 7) * 4;
            #pragma unroll
            for (int p = 0; p < 2; ++p) {
                const int rr = r + p * 32;
                const float4 a = *(const float4*)&A[(size_t)(row0 + rr) * 512 + kc + kq];
                At[kq + 0][rr] = a.x; At[kq + 1][rr] = a.y;
                At[kq + 2][rr] = a.z; At[kq + 3][rr] = a.w;
            }
        }
        {   // stage B: 32 k x 64 cols
            const int k  = tid >> 3;
            const int cq = (tid & 7) * 8;
            *(float4*)&Bt[k][cq]     = *(const float4*)&Wj1[(size_t)(kc + k) * JOIND + col0 + cq];
            *(float4*)&Bt[k][cq + 4] = *(const float4*)&Wj1[(size_t)(kc + k) * JOIND + col0 + cq + 4];
        }
        __syncthreads();
        #pragma unroll 4
        for (int k = 0; k < 32; ++k) {
            const float4 av = *(const float4*)&At[k][ty * 4];
            const float4 bv = *(const float4*)&Bt[k][tx * 4];
            const float aa[4] = {av.x, av.y, av.z, av.w};
            const float bb[4] = {bv.x, bv.y, bv.z, bv.w};
            #pragma unroll
            for (int i = 0; i < 4; ++i)
                #pragma unroll
                for (int j = 0; j < 4; ++j)
                    acc[i][j] = fmaf(aa[i], bb[j], acc[i][j]);
        }
        __syncthreads();
    }
    #pragma unroll
    for (int i = 0; i < 4; ++i) {
        const float4 o = {acc[i][0], acc[i][1], acc[i][2], acc[i][3]};
        *(float4*)&eproj[(size_t)(row0 + ty * 4 + i) * 512 + col0 + tx * 4] = o;
    }
}

// ---------------------------------------------------------------------------
// Kernel C: joint. Block = 8t x 8u x 128v tile; 256 threads (16x16).
// h rows computed on the fly into transposed LDS; Wj2 chunk in LDS.
// Thread: rows 4*ty..+3, cols {4*tx..+3} U {64+4*tx..+3}. K-chunks of 32.
// Fully-masked blocks: coalesced zero-fill and exit.
// ---------------------------------------------------------------------------
__global__ __launch_bounds__(256) void joint_kernel(
    const float* __restrict__ Eproj, const float* __restrict__ Pproj,
    const float* __restrict__ Wj2, const float* __restrict__ bj2,
    const int* __restrict__ esz, const int* __restrict__ tsz,
    float* __restrict__ out)
{
    const int b  = blockIdx.z;
    const int t0 = blockIdx.y * 8;
    const int u0 = blockIdx.x * 8;
    const int tid = threadIdx.x;
    const int es = esz[b], ts = tsz[b];
    const int nu = (UP1 - u0 < 8) ? (UP1 - u0) : 8;   // 8 or 1

    if (t0 >= es || u0 > ts) {   // entire tile masked -> zero fill
        const int total = 8 * nu * 32;                 // float4 count
        const float4 z = {0.f, 0.f, 0.f, 0.f};
        for (int idx = tid; idx < total; idx += 256) {
            const int slot = idx & 31;
            const int r = idx >> 5;
            const int tt = (nu == 8) ? (r >> 3) : r;
            const int uu = (nu == 8) ? (r & 7) : 0;
            *(float4*)&out[(((size_t)(b * NT + t0 + tt) * UP1 + (u0 + uu)) << 7) + slot * 4] = z;
        }
        return;
    }

    __shared__ float hT[32][64];    // [k][r] transposed h chunk
    __shared__ float Ws[32][132];   // [k][c] Wj2 chunk, padded stride

    const int tx = tid & 15, ty = tid >> 4;
    // h-staging assignment: thread covers row sr, k-range skq..skq+7
    const int sr  = tid & 63;
    const int st  = t0 + (sr >> 3);
    const int su0 = u0 + (sr & 7);
    const int su  = (su0 < UP1) ? su0 : (UP1 - 1);     // clamp (u-tile 8)
    const int skq = (tid >> 6) * 8;
    const float* __restrict__ Erow = &Eproj[((size_t)b * NT + st) * 512];
    const float* __restrict__ Prow = &Pproj[((size_t)b * UP1 + su) * 512];
    const int wk = tid >> 3;          // 0..31 (W staging)
    const int wq = (tid & 7) * 4;

    float acc[4][8] = {};
    for (int kc = 0; kc < 512; kc += 32) {
        {   // h chunk: relu(Eproj + Pproj), Pproj already holds +bj1
            const float4 e0 = *(const float4*)&Erow[kc + skq];
            const float4 e1 = *(const float4*)&Erow[kc + skq + 4];
            const float4 p0 = *(const float4*)&Prow[kc + skq];
            const float4 p1 = *(const float4*)&Prow[kc + skq + 4];
            hT[skq + 0][sr] = frelu(e0.x + p0.x);
            hT[skq + 1][sr] = frelu(e0.y + p0.y);
            hT[skq + 2][sr] = frelu(e0.z + p0.z);
            hT[skq + 3][sr] = frelu(e0.w + p0.w);
            hT[skq + 4][sr] = frelu(e1.x + p1.x);
            hT[skq + 5][sr] = frelu(e1.y + p1.y);
            hT[skq + 6][sr] = frelu(e1.z + p1.z);
            hT[skq + 7][sr] = frelu(e1.w + p1.w);
        }
        {   // Wj2 chunk: 32 k x 128 v
            #pragma unroll
            for (int i = 0; i < 4; ++i)
                *(float4*)&Ws[wk][i * 32 + wq] =
                    *(const float4*)&Wj2[(size_t)(kc + wk) * 128 + i * 32 + wq];
        }
        __syncthreads();
        #pragma unroll 4
        for (int k = 0; k < 32; ++k) {
            const float4 av = *(const float4*)&hT[k][ty * 4];
            const float4 b0 = *(const float4*)&Ws[k][tx * 4];
            const float4 b1 = *(const float4*)&Ws[k][64 + tx * 4];
            const float aa[4] = {av.x, av.y, av.z, av.w};
            const float bb[8] = {b0.x, b0.y, b0.z, b0.w, b1.x, b1.y, b1.z, b1.w};
            #pragma unroll
            for (int i = 0; i < 4; ++i)
                #pragma unroll
                for (int j = 0; j < 8; ++j)
                    acc[i][j] = fmaf(aa[i], bb[j], acc[i][j]);
        }
        __syncthreads();
    }

    // epilogue: + bj2, mask, store
    const float4 bja = *(const float4*)&bj2[tx * 4];
    const float4 bjb = *(const float4*)&bj2[64 + tx * 4];
    const float4 z = {0.f, 0.f, 0.f, 0.f};
    #pragma unroll
    for (int i = 0; i < 4; ++i) {
        const int r = ty * 4 + i;
        const int t = t0 + (r >> 3);
        const int u = u0 + (r & 7);
        if (u >= UP1) continue;                       // row doesn't exist
        const bool valid = (t < es) && (u <= ts);
        float4 o0 = z, o1 = z;
        if (valid) {
            o0 = make_float4(acc[i][0] + bja.x, acc[i][1] + bja.y,
                             acc[i][2] + bja.z, acc[i][3] + bja.w);
            o1 = make_float4(acc[i][4] + bjb.x, acc[i][5] + bjb.y,
                             acc[i][6] + bjb.z, acc[i][7] + bjb.w);
        }
        float* __restrict__ orow = &out[((size_t)(b * NT + t) * UP1 + u) << 7];
        *(float4*)&orow[tx * 4]      = o0;
        *(float4*)&orow[64 + tx * 4] = o1;
    }
}

// ---------------------------------------------------------------------------
extern "C" void kernel_launch(void* const* d_in, const int* in_sizes, int n_in,
                              void* d_out, int out_size, void* d_ws, size_t ws_size,
                              hipStream_t stream) {
    (void)in_sizes; (void)n_in; (void)out_size; (void)ws_size;
    const float* enc     = (const float*)d_in[0];
    const int*   esz     = (const int*)d_in[1];
    const int*   targets = (const int*)d_in[2];
    const int*   tsz     = (const int*)d_in[3];
    const float* emb     = (const float*)d_in[4];
    const float* W1      = (const float*)d_in[5];
    const float* b1      = (const float*)d_in[6];
    const float* W2      = (const float*)d_in[7];
    const float* b2      = (const float*)d_in[8];
    const float* Wj1     = (const float*)d_in[9];
    const float* bj1     = (const float*)d_in[10];
    const float* Wj2     = (const float*)d_in[11];
    const float* bj2     = (const float*)d_in[12];
    float* out = (float*)d_out;

    float* eproj = (float*)d_ws;                       // 4096*512 f32 = 8 MB
    float* pproj = eproj + (size_t)NB * NT * JOIND;    // 520*512 f32 = 1 MB

    pred_net_kernel<<<NB * UP1, 256, 0, stream>>>(targets, tsz, emb, W1, b1,
                                                  W2, b2, Wj1, bj1, pproj);
    enc_proj_kernel<<<dim3(8, 64), 256, 0, stream>>>(enc, Wj1, esz, eproj);
    joint_kernel<<<dim3(9, 64, 8), 256, 0, stream>>>(eproj, pproj, Wj2, bj2,
                                                     esz, tsz, out);
}

// Round 2
// 278.603 us; speedup vs baseline: 1.1693x; 1.1693x over previous
//
#include <hip/hip_runtime.h>

// FFNN Transducer fused forward.
// R2: joint rewritten as bf16 MFMA with hi/lo truncation split (3-term),
//     fp32-equivalent accuracy. enc_proj / pred_net unchanged from R1.
// Inputs (setup_inputs order):
//  0 encoder_states (8,512,512) f32     1 encoder_states_size (8) i32
//  2 targets (8,64) i32                 3 targets_size (8) i32
//  4 emb (128,128) f32                  5 W1 (256,256)  6 b1 (256)
//  7 W2 (256,256)  8 b2 (256)           9 Wj1 (768,512) 10 bj1 (512)
// 11 Wj2 (512,128) 12 bj2 (128)
// Output: (8,512,65,128) f32, masked.
// ws: eproj 8MB | pproj 1.04MB | Wj2hiT 128KB | Wj2loT 128KB

#define VOCAB 128
#define EMBD  128
#define ENCD  512
#define PREDD 256
#define JOIND 512
#define NB    8
#define NT    512
#define NUT   64
#define UP1   65

typedef __bf16 bf16x8 __attribute__((ext_vector_type(8)));
typedef float  f32x4  __attribute__((ext_vector_type(4)));

__device__ __forceinline__ float frelu(float x) { return x > 0.f ? x : 0.f; }

// Truncation split of two f32 into packed bf16-hi pair and bf16-lo pair.
// x = hi + r exactly (bit-mask), lo = trunc_bf16(r): pair error ~2^-17|x|.
__device__ __forceinline__ void split2(float x0, float x1,
                                       unsigned& hi, unsigned& lo) {
    unsigned u0 = __float_as_uint(x0), u1 = __float_as_uint(x1);
    hi = (u0 >> 16) | (u1 & 0xFFFF0000u);
    float r0 = x0 - __uint_as_float(u0 & 0xFFFF0000u);
    float r1 = x1 - __uint_as_float(u1 & 0xFFFF0000u);
    lo = (__float_as_uint(r0) >> 16) | (__float_as_uint(r1) & 0xFFFF0000u);
}

// ---------------------------------------------------------------------------
// Prep: Wj2 (512x128 f32, [k][n]) -> transposed hi/lo bf16 [n][k] (512 each).
// ---------------------------------------------------------------------------
__global__ __launch_bounds__(256) void prep_wj2(
    const float* __restrict__ Wj2,
    unsigned short* __restrict__ WhT, unsigned short* __restrict__ WlT)
{
    const int idx = blockIdx.x * 256 + threadIdx.x;  // n*512 + k
    const int n = idx >> 9, k = idx & 511;
    const float x = Wj2[k * VOCAB + n];
    const unsigned u = __float_as_uint(x);
    WhT[idx] = (unsigned short)(u >> 16);
    const float r = x - __uint_as_float(u & 0xFFFF0000u);
    WlT[idx] = (unsigned short)(__float_as_uint(r) >> 16);
}

// ---------------------------------------------------------------------------
// Kernel A: prediction network + projection through Wp (=Wj1[512:768]) + bj1.
// ---------------------------------------------------------------------------
__global__ __launch_bounds__(256) void pred_net_kernel(
    const int* __restrict__ targets, const int* __restrict__ tsz,
    const float* __restrict__ emb,
    const float* __restrict__ W1, const float* __restrict__ b1,
    const float* __restrict__ W2, const float* __restrict__ b2,
    const float* __restrict__ Wj1, const float* __restrict__ bj1,
    float* __restrict__ pproj)
{
    const int row = blockIdx.x;          // 0..519
    const int b = row / UP1, u = row % UP1;
    if (u > tsz[b]) return;
    const int tid = threadIdx.x;
    __shared__ float e_s[256], p_s[256], q_s[256];

    const int c0 = (u >= 1) ? targets[b * NUT + u - 1] : (VOCAB - 1);
    const int c1 = (u >= 2) ? targets[b * NUT + u - 2] : (VOCAB - 1);
    e_s[tid] = (tid < EMBD) ? emb[c0 * EMBD + tid] : emb[c1 * EMBD + (tid - EMBD)];
    __syncthreads();

    {
        float a0 = 0.f, a1 = 0.f, a2 = 0.f, a3 = 0.f;
        #pragma unroll 8
        for (int k = 0; k < 256; k += 4) {
            a0 = fmaf(e_s[k + 0], W1[(k + 0) * PREDD + tid], a0);
            a1 = fmaf(e_s[k + 1], W1[(k + 1) * PREDD + tid], a1);
            a2 = fmaf(e_s[k + 2], W1[(k + 2) * PREDD + tid], a2);
            a3 = fmaf(e_s[k + 3], W1[(k + 3) * PREDD + tid], a3);
        }
        p_s[tid] = frelu((a0 + a1) + (a2 + a3) + b1[tid]);
    }
    __syncthreads();

    {
        float a0 = 0.f, a1 = 0.f, a2 = 0.f, a3 = 0.f;
        #pragma unroll 8
        for (int k = 0; k < 256; k += 4) {
            a0 = fmaf(p_s[k + 0], W2[(k + 0) * PREDD + tid], a0);
            a1 = fmaf(p_s[k + 1], W2[(k + 1) * PREDD + tid], a1);
            a2 = fmaf(p_s[k + 2], W2[(k + 2) * PREDD + tid], a2);
            a3 = fmaf(p_s[k + 3], W2[(k + 3) * PREDD + tid], a3);
        }
        q_s[tid] = frelu((a0 + a1) + (a2 + a3) + b2[tid]);
    }
    __syncthreads();

    #pragma unroll
    for (int h = 0; h < 2; ++h) {
        const int j = tid + h * 256;
        float a0 = 0.f, a1 = 0.f, a2 = 0.f, a3 = 0.f;
        #pragma unroll 8
        for (int k = 0; k < 256; k += 4) {
            a0 = fmaf(q_s[k + 0], Wj1[(size_t)(ENCD + k + 0) * JOIND + j], a0);
            a1 = fmaf(q_s[k + 1], Wj1[(size_t)(ENCD + k + 1) * JOIND + j], a1);
            a2 = fmaf(q_s[k + 2], Wj1[(size_t)(ENCD + k + 2) * JOIND + j], a2);
            a3 = fmaf(q_s[k + 3], Wj1[(size_t)(ENCD + k + 3) * JOIND + j], a3);
        }
        pproj[(size_t)row * JOIND + j] = (a0 + a1) + (a2 + a3) + bj1[j];
    }
}

// ---------------------------------------------------------------------------
// Kernel B: enc_proj = encoder_states @ We (=Wj1[0:512]).  (unchanged R1)
// ---------------------------------------------------------------------------
__global__ __launch_bounds__(256) void enc_proj_kernel(
    const float* __restrict__ A, const float* __restrict__ Wj1,
    const int* __restrict__ esz, float* __restrict__ eproj)
{
    const int rTile = blockIdx.y, cTile = blockIdx.x;
    const int b = rTile >> 3;
    const int t0 = (rTile & 7) * 64;
    if (t0 >= esz[b]) return;
    const int row0 = rTile * 64, col0 = cTile * 64;
    const int tid = threadIdx.x;
    const int tx = tid & 15, ty = tid >> 4;

    __shared__ float At[32][68];
    __shared__ float Bt[32][64];

    float acc[4][4] = {};
    for (int kc = 0; kc < 512; kc += 32) {
        {
            const int r  = tid >> 3;
            const int kq = (tid & 7) * 4;
            #pragma unroll
            for (int p = 0; p < 2; ++p) {
                const int rr = r + p * 32;
                const float4 a = *(const float4*)&A[(size_t)(row0 + rr) * 512 + kc + kq];
                At[kq + 0][rr] = a.x; At[kq + 1][rr] = a.y;
                At[kq + 2][rr] = a.z; At[kq + 3][rr] = a.w;
            }
        }
        {
            const int k  = tid >> 3;
            const int cq = (tid & 7) * 8;
            *(float4*)&Bt[k][cq]     = *(const float4*)&Wj1[(size_t)(kc + k) * JOIND + col0 + cq];
            *(float4*)&Bt[k][cq + 4] = *(const float4*)&Wj1[(size_t)(kc + k) * JOIND + col0 + cq + 4];
        }
        __syncthreads();
        #pragma unroll 4
        for (int k = 0; k < 32; ++k) {
            const float4 av = *(const float4*)&At[k][ty * 4];
            const float4 bv = *(const float4*)&Bt[k][tx * 4];
            const float aa[4] = {av.x, av.y, av.z, av.w};
            const float bb[4] = {bv.x, bv.y, bv.z, bv.w};
            #pragma unroll
            for (int i = 0; i < 4; ++i)
                #pragma unroll
                for (int j = 0; j < 4; ++j)
                    acc[i][j] = fmaf(aa[i], bb[j], acc[i][j]);
        }
        __syncthreads();
    }
    #pragma unroll
    for (int i = 0; i < 4; ++i) {
        const float4 o = {acc[i][0], acc[i][1], acc[i][2], acc[i][3]};
        *(float4*)&eproj[(size_t)(row0 + ty * 4 + i) * 512 + col0 + tx * 4] = o;
    }
}

// ---------------------------------------------------------------------------
// Kernel C: joint via MFMA. Block tile: 256 rows (32t x 8u) x 128 v, K=512.
// 4 waves; wave (wr,wc) owns rows wr*128..+128, cols wc*64..+64.
// K-chunks of 32. LDS: h hi/lo [256][k32] + Wj2 hi/lo [128][k32],
// all rows padded to 80B (40 ushorts) -> 2-way bank conflicts only.
// 3-term MFMA: AhBh + AlBh + AhBl (fp32-equivalent).
// ---------------------------------------------------------------------------
__global__ __launch_bounds__(256, 2) void joint_kernel(
    const float* __restrict__ Eproj, const float* __restrict__ Pproj,
    const unsigned short* __restrict__ WhT, const unsigned short* __restrict__ WlT,
    const float* __restrict__ bj2,
    const int* __restrict__ esz, const int* __restrict__ tsz,
    float* __restrict__ out)
{
    const int b  = blockIdx.z;
    const int t0 = blockIdx.y * 32;
    const int u0 = blockIdx.x * 8;
    const int tid = threadIdx.x;
    const int es = esz[b], ts = tsz[b];
    const int nu = (UP1 - u0 < 8) ? (UP1 - u0) : 8;   // 8 or 1

    if (t0 >= es || u0 > ts) {   // fully masked -> zero fill
        const float4 z = {0.f, 0.f, 0.f, 0.f};
        const int total = 32 * nu * 32;               // float4 count
        for (int idx = tid; idx < total; idx += 256) {
            const int slot = idx & 31;
            const int rr = idx >> 5;
            const int tt = (nu == 8) ? (rr >> 3) : rr;
            const int uu = (nu == 8) ? (rr & 7) : 0;
            *(float4*)&out[(((size_t)(b * NT + t0 + tt) * UP1 + (u0 + uu)) << 7) + slot * 4] = z;
        }
        return;
    }

    __shared__ __align__(16) unsigned short AhS[256 * 40];  // 20KB
    __shared__ __align__(16) unsigned short AlS[256 * 40];  // 20KB
    __shared__ __align__(16) unsigned short BhS[128 * 40];  // 10KB
    __shared__ __align__(16) unsigned short BlS[128 * 40];  // 10KB

    // staging identity: thread r owns h-row r = (t,u) pair
    const int r  = tid;
    const int st = t0 + (r >> 3);
    int su = u0 + (r & 7); if (su > NUT) su = NUT;    // clamp (u0=64 tile)
    const float* __restrict__ Erow = Eproj + (size_t)(b * NT + st) * JOIND;
    const float* __restrict__ Prow = Pproj + (size_t)(b * UP1 + su) * JOIND;

    const int lane = tid & 63;
    const int w  = tid >> 6;
    const int wr = w >> 1, wc = w & 1;
    const int l15 = lane & 15, lj = lane >> 4;

    f32x4 acc[8][4];
    #pragma unroll
    for (int mt = 0; mt < 8; ++mt)
        #pragma unroll
        for (int nt = 0; nt < 4; ++nt)
            acc[mt][nt] = (f32x4){0.f, 0.f, 0.f, 0.f};

    for (int kc = 0; kc < 512; kc += 32) {
        // ---- stage h chunk: x = relu(e+p), split hi/lo, 8 elems per step
        #pragma unroll
        for (int q = 0; q < 4; ++q) {
            const float4 e0 = *(const float4*)(Erow + kc + q * 8);
            const float4 e1 = *(const float4*)(Erow + kc + q * 8 + 4);
            const float4 p0 = *(const float4*)(Prow + kc + q * 8);
            const float4 p1 = *(const float4*)(Prow + kc + q * 8 + 4);
            const float x0 = frelu(e0.x + p0.x), x1 = frelu(e0.y + p0.y);
            const float x2 = frelu(e0.z + p0.z), x3 = frelu(e0.w + p0.w);
            const float x4 = frelu(e1.x + p1.x), x5 = frelu(e1.y + p1.y);
            const float x6 = frelu(e1.z + p1.z), x7 = frelu(e1.w + p1.w);
            unsigned h0, h1, h2, h3, l0, l1, l2, l3;
            split2(x0, x1, h0, l0); split2(x2, x3, h1, l1);
            split2(x4, x5, h2, l2); split2(x6, x7, h3, l3);
            *(uint4*)&AhS[r * 40 + q * 8] = make_uint4(h0, h1, h2, h3);
            *(uint4*)&AlS[r * 40 + q * 8] = make_uint4(l0, l1, l2, l3);
        }
        // ---- stage Wj2 chunk (pre-split, [n][k] layout in ws)
        {
            const int n = tid >> 1, half = tid & 1;
            const size_t g = (size_t)n * 512 + kc + half * 16;
            const uint4 bh0 = *(const uint4*)(WhT + g);
            const uint4 bh1 = *(const uint4*)(WhT + g + 8);
            const uint4 bl0 = *(const uint4*)(WlT + g);
            const uint4 bl1 = *(const uint4*)(WlT + g + 8);
            *(uint4*)&BhS[n * 40 + half * 16]     = bh0;
            *(uint4*)&BhS[n * 40 + half * 16 + 8] = bh1;
            *(uint4*)&BlS[n * 40 + half * 16]     = bl0;
            *(uint4*)&BlS[n * 40 + half * 16 + 8] = bl1;
        }
        __syncthreads();

        // ---- fragments + MFMA
        bf16x8 bh[4], bl[4];
        #pragma unroll
        for (int nt = 0; nt < 4; ++nt) {
            const int n = wc * 64 + nt * 16 + l15;
            const int off = n * 40 + lj * 8;
            bh[nt] = *(const bf16x8*)&BhS[off];
            bl[nt] = *(const bf16x8*)&BlS[off];
        }
        #pragma unroll
        for (int mt = 0; mt < 8; ++mt) {
            const int m = wr * 128 + mt * 16 + l15;
            const int off = m * 40 + lj * 8;
            const bf16x8 ah = *(const bf16x8*)&AhS[off];
            const bf16x8 al = *(const bf16x8*)&AlS[off];
            #pragma unroll
            for (int nt = 0; nt < 4; ++nt) {
                acc[mt][nt] = __builtin_amdgcn_mfma_f32_16x16x32_bf16(ah, bh[nt], acc[mt][nt], 0, 0, 0);
                acc[mt][nt] = __builtin_amdgcn_mfma_f32_16x16x32_bf16(al, bh[nt], acc[mt][nt], 0, 0, 0);
                acc[mt][nt] = __builtin_amdgcn_mfma_f32_16x16x32_bf16(ah, bl[nt], acc[mt][nt], 0, 0, 0);
            }
        }
        __syncthreads();
    }

    // ---- epilogue: +bj2, mask, store (D layout: col=lane&15, row=lj*4+reg)
    float bj[4];
    #pragma unroll
    for (int nt = 0; nt < 4; ++nt) bj[nt] = bj2[wc * 64 + nt * 16 + l15];

    #pragma unroll
    for (int mt = 0; mt < 8; ++mt) {
        #pragma unroll
        for (int r4 = 0; r4 < 4; ++r4) {
            const int row = wr * 128 + mt * 16 + lj * 4 + r4;
            const int t = t0 + (row >> 3);
            const int u = u0 + (row & 7);
            if (u >= UP1) continue;                  // u0=64 tiles only
            const bool valid = (t < es) && (u <= ts);
            float* __restrict__ orow =
                out + ((size_t)(b * NT + t) * UP1 + u) * VOCAB + wc * 64 + l15;
            #pragma unroll
            for (int nt = 0; nt < 4; ++nt)
                orow[nt * 16] = valid ? (acc[mt][nt][r4] + bj[nt]) : 0.f;
        }
    }
}

// ---------------------------------------------------------------------------
extern "C" void kernel_launch(void* const* d_in, const int* in_sizes, int n_in,
                              void* d_out, int out_size, void* d_ws, size_t ws_size,
                              hipStream_t stream) {
    (void)in_sizes; (void)n_in; (void)out_size; (void)ws_size;
    const float* enc     = (const float*)d_in[0];
    const int*   esz     = (const int*)d_in[1];
    const int*   targets = (const int*)d_in[2];
    const int*   tsz     = (const int*)d_in[3];
    const float* emb     = (const float*)d_in[4];
    const float* W1      = (const float*)d_in[5];
    const float* b1      = (const float*)d_in[6];
    const float* W2      = (const float*)d_in[7];
    const float* b2      = (const float*)d_in[8];
    const float* Wj1     = (const float*)d_in[9];
    const float* bj1     = (const float*)d_in[10];
    const float* Wj2     = (const float*)d_in[11];
    const float* bj2     = (const float*)d_in[12];
    float* out = (float*)d_out;

    // workspace layout
    float* eproj = (float*)d_ws;                                  // 8 MB
    float* pproj = eproj + (size_t)NB * NT * JOIND;               // 1.04 MB
    unsigned short* WhT = (unsigned short*)(pproj + (size_t)NB * UP1 * JOIND);
    unsigned short* WlT = WhT + (size_t)VOCAB * JOIND;            // 128 KB each

    prep_wj2<<<(VOCAB * JOIND) / 256, 256, 0, stream>>>(Wj2, WhT, WlT);
    pred_net_kernel<<<NB * UP1, 256, 0, stream>>>(targets, tsz, emb, W1, b1,
                                                  W2, b2, Wj1, bj1, pproj);
    enc_proj_kernel<<<dim3(8, 64), 256, 0, stream>>>(enc, Wj1, esz, eproj);
    joint_kernel<<<dim3(9, 16, 8), 256, 0, stream>>>(eproj, pproj, WhT, WlT,
                                                     bj2, esz, tsz, out);
}